// Round 12
// baseline (79.865 us; speedup 1.0000x reference)
//
#include <hip/hip_runtime.h>

#define Hd 128
#define Wd 128
#define Cd 64
#define COd 64
#define Bd 4
#define HWd (Hd*Wd)

typedef __attribute__((ext_vector_type(8))) _Float16 half8;
typedef __attribute__((ext_vector_type(2))) _Float16 h2;
typedef __attribute__((ext_vector_type(4))) float    f32x4;

// Static device scratch (fp16 everywhere).
__device__ __align__(16) _Float16 g_wh[COd*576];                 // W[co][k], k=t*64+c
__device__ __align__(16) _Float16 g_woffh[16*576];               // w_off padded to 16 rows
__device__ __align__(16) unsigned short g_xt[(size_t)Bd*HWd*Cd]; // fp16 NHWC x

static __device__ __forceinline__ unsigned cvtpkh(float lo, float hi) {
    unsigned r;
    asm("v_cvt_pkrtz_f16_f32 %0, %1, %2" : "=v"(r) : "v"(lo), "v"(hi));
    return r;
}
static __device__ __forceinline__ h2 ash2(unsigned u) {
    union { unsigned u; h2 h; } x; x.u = u; return x.h;
}
static __device__ __forceinline__ unsigned ash2u(h2 h) {
    union { h2 h; unsigned u; } x; x.h = h; return x.u;
}

// Prep: [0,512) NHWC fp16 ; [512,656) W->fp16 ; [656,692) w_off padded fp16.
__global__ __launch_bounds__(256) void k_prep(const float* __restrict__ x,
                                              const float* __restrict__ weight,
                                              const float* __restrict__ w_off) {
    int bid = blockIdx.x;
    if (bid < 512) {
        int b = bid >> 7, y = bid & 127;
        int px = threadIdx.x & 127;
        int h  = threadIdx.x >> 7;
        const float* xb = x + (size_t)b*Cd*HWd + y*Wd + px;
        unsigned short* ob = g_xt + ((size_t)(b*HWd) + y*Wd + px)*Cd + h*32;
        #pragma unroll
        for (int oct = 0; oct < 4; ++oct) {
            unsigned pk[4];
            #pragma unroll
            for (int e = 0; e < 4; ++e) {
                float v0 = xb[(size_t)(h*32 + oct*8 + 2*e    )*HWd];
                float v1 = xb[(size_t)(h*32 + oct*8 + 2*e + 1)*HWd];
                pk[e] = cvtpkh(v0, v1);
            }
            *(uint4*)(ob + oct*8) = make_uint4(pk[0], pk[1], pk[2], pk[3]);
        }
    } else if (bid < 656) {
        int g = (bid - 512)*256 + threadIdx.x;     // 64*576
        if (g < COd*576) {
            int co = g / 576, k = g % 576;
            int t = k >> 6, c = k & 63;            // k = t*64 + c
            g_wh[g] = (_Float16)weight[(co*Cd + c)*9 + t];
        }
    } else {
        int g = (bid - 656)*256 + threadIdx.x;     // 16*576 = 9216
        if (g < 16*576) {
            int row = g / 576, k = g % 576;
            int t = k >> 6, c = k & 63;
            g_woffh[g] = (row < 4) ? (_Float16)w_off[(row*Cd + c)*9 + t] : (_Float16)0.f;
        }
    }
}

// Fused offsets+deform, barrier-free. Wave = 16 px x 64 co; per-wave LDS staging.
__global__ __launch_bounds__(256, 4) void k_main(const float* __restrict__ b_off,
                                                 const float* __restrict__ bias,
                                                 float* __restrict__ out) {
    __shared__ uint4 lds[4*2*128];       // [wave][buf][px*8 + hg^swz] = 16 KB
    int orig = blockIdx.x;               // 1024, XCD-banded (bijective)
    int xcd = orig & 7, slot = orig >> 3;
    int g = xcd*2 + (slot >> 6);
    int s = slot & 63;
    int b  = g >> 2;
    int i  = (g & 3)*32 + (s >> 1);
    int j0 = (s & 1) << 6;

    int w = threadIdx.x >> 6, l = threadIdx.x & 63;
    int p0 = j0 + w*16;
    const unsigned short* xb = g_xt + (size_t)b*HWd*Cd;
    uint4* lw = lds + w*256;

    int pc = l & 15, q = l >> 4;

    // ---- head: offsets mini-GEMM for this wave's 16 px (r9-validated form) ----
    f32x4 oacc = {0.f, 0.f, 0.f, 0.f};
    {
        int jh = p0 + pc;
        const _Float16* arow = g_woffh + pc*576 + q*8;
        #pragma unroll
        for (int t = 0; t < 9; ++t) {
            int yy = i + t/3 - 1, xx = jh + t%3 - 1;
            bool ok = (yy >= 0) & (yy <= 127) & (xx >= 0) & (xx <= 127);
            const unsigned short* p = xb + (size_t)(yy*Wd + xx)*Cd + q*8;
            uint4 u0 = ok ? *(const uint4*)p        : make_uint4(0,0,0,0);
            uint4 u1 = ok ? *(const uint4*)(p + 32) : make_uint4(0,0,0,0);
            half8 a0 = *(const half8*)(arow + (2*t    )*32);
            half8 a1 = *(const half8*)(arow + (2*t + 1)*32);
            oacc = __builtin_amdgcn_mfma_f32_16x16x32_f16(a0, *(half8*)&u0, oacc, 0, 0, 0);
            oacc = __builtin_amdgcn_mfma_f32_16x16x32_f16(a1, *(half8*)&u1, oacc, 0, 0, 0);
        }
    }
    // Broadcast: lanes 0..15 (q==0) hold rows 0..3 for px=lane. Two gather rounds.
    int oct = l & 7, px8 = l >> 3;       // gather identity: 8 px x 8 oct
    int s0i = px8, s1i = 8 + px8;
    float off0_0 = __shfl(oacc[0], s0i, 64) + b_off[0];
    float off1_0 = __shfl(oacc[1], s0i, 64) + b_off[1];
    float sc1_0  = fmaxf(__shfl(oacc[2], s0i, 64) + b_off[2], 0.f) + 1.f;
    float sc2_0  = fmaxf(__shfl(oacc[3], s0i, 64) + b_off[3], 0.f) + 1.f;
    float off0_1 = __shfl(oacc[0], s1i, 64) + b_off[0];
    float off1_1 = __shfl(oacc[1], s1i, 64) + b_off[1];
    float sc1_1  = fmaxf(__shfl(oacc[2], s1i, 64) + b_off[2], 0.f) + 1.f;
    float sc2_1  = fmaxf(__shfl(oacc[3], s1i, 64) + b_off[3], 0.f) + 1.f;

    int jr0 = p0 + px8, jr1 = p0 + 8 + px8;
    int swz = px8 & 7;                   // same for both rounds ((8+px8)&7 == px8&7)

    f32x4 accm[4];
    #pragma unroll
    for (int cg = 0; cg < 4; ++cg) accm[cg] = (f32x4){0.f, 0.f, 0.f, 0.f};

    #pragma unroll
    for (int t = 0; t < 9; ++t) {
        const float ky = (float)(t/3 - 1), kx = (float)(t%3 - 1);
        // ---- round-0 + round-1 gathers (8 full-line uint4 loads in flight) ----
        uint4 u00, u01, u10, u11, v00, v01, v10, v11;
        h2 H00, H01, H10, H11, G00, G01, G10, G11;
        {
            float ys = (float)(i - 1) + ky*sc1_0 + off0_0;
            float xs = (float)(jr0 - 1) + kx*sc2_0 + off1_0;
            float y0f = floorf(ys), x0f = floorf(xs);
            float wy = ys - y0f, wx = xs - x0f;
            float vy0 = (y0f >=  0.f && y0f <= 127.f) ? 1.f : 0.f;
            float vy1 = (y0f >= -1.f && y0f <= 126.f) ? 1.f : 0.f;
            float vx0 = (x0f >=  0.f && x0f <= 127.f) ? 1.f : 0.f;
            float vx1 = (x0f >= -1.f && x0f <= 126.f) ? 1.f : 0.f;
            float w00 = (1.f-wy)*(1.f-wx)*vy0*vx0, w01 = (1.f-wy)*wx*vy0*vx1;
            float w10 = wy*(1.f-wx)*vy1*vx0,       w11 = wy*wx*vy1*vx1;
            H00 = ash2(cvtpkh(w00, w00)); H01 = ash2(cvtpkh(w01, w01));
            H10 = ash2(cvtpkh(w10, w10)); H11 = ash2(cvtpkh(w11, w11));
            int iy0 = min(max((int)y0f, 0), 127), iy1 = min(max((int)y0f + 1, 0), 127);
            int ix0 = min(max((int)x0f, 0), 127), ix1 = min(max((int)x0f + 1, 0), 127);
            u00 = *(const uint4*)(xb + (size_t)(iy0*Wd + ix0)*Cd + oct*8);
            u01 = *(const uint4*)(xb + (size_t)(iy0*Wd + ix1)*Cd + oct*8);
            u10 = *(const uint4*)(xb + (size_t)(iy1*Wd + ix0)*Cd + oct*8);
            u11 = *(const uint4*)(xb + (size_t)(iy1*Wd + ix1)*Cd + oct*8);
        }
        {
            float ys = (float)(i - 1) + ky*sc1_1 + off0_1;
            float xs = (float)(jr1 - 1) + kx*sc2_1 + off1_1;
            float y0f = floorf(ys), x0f = floorf(xs);
            float wy = ys - y0f, wx = xs - x0f;
            float vy0 = (y0f >=  0.f && y0f <= 127.f) ? 1.f : 0.f;
            float vy1 = (y0f >= -1.f && y0f <= 126.f) ? 1.f : 0.f;
            float vx0 = (x0f >=  0.f && x0f <= 127.f) ? 1.f : 0.f;
            float vx1 = (x0f >= -1.f && x0f <= 126.f) ? 1.f : 0.f;
            float w00 = (1.f-wy)*(1.f-wx)*vy0*vx0, w01 = (1.f-wy)*wx*vy0*vx1;
            float w10 = wy*(1.f-wx)*vy1*vx0,       w11 = wy*wx*vy1*vx1;
            G00 = ash2(cvtpkh(w00, w00)); G01 = ash2(cvtpkh(w01, w01));
            G10 = ash2(cvtpkh(w10, w10)); G11 = ash2(cvtpkh(w11, w11));
            int iy0 = min(max((int)y0f, 0), 127), iy1 = min(max((int)y0f + 1, 0), 127);
            int ix0 = min(max((int)x0f, 0), 127), ix1 = min(max((int)x0f + 1, 0), 127);
            v00 = *(const uint4*)(xb + (size_t)(iy0*Wd + ix0)*Cd + oct*8);
            v01 = *(const uint4*)(xb + (size_t)(iy0*Wd + ix1)*Cd + oct*8);
            v10 = *(const uint4*)(xb + (size_t)(iy1*Wd + ix0)*Cd + oct*8);
            v11 = *(const uint4*)(xb + (size_t)(iy1*Wd + ix1)*Cd + oct*8);
        }
        // ---- pack + per-wave LDS write (no barrier: same-wave producer/consumer) ----
        {
            unsigned a00[4] = {u00.x,u00.y,u00.z,u00.w}, a01[4] = {u01.x,u01.y,u01.z,u01.w};
            unsigned a10[4] = {u10.x,u10.y,u10.z,u10.w}, a11[4] = {u11.x,u11.y,u11.z,u11.w};
            unsigned pk[4];
            #pragma unroll
            for (int e = 0; e < 4; ++e) {
                h2 r = ash2(a00[e])*H00 + ash2(a01[e])*H01
                     + ash2(a10[e])*H10 + ash2(a11[e])*H11;
                pk[e] = ash2u(r);
            }
            lw[(t&1)*128 + px8*8 + (oct ^ swz)] = make_uint4(pk[0], pk[1], pk[2], pk[3]);
        }
        {
            unsigned a00[4] = {v00.x,v00.y,v00.z,v00.w}, a01[4] = {v01.x,v01.y,v01.z,v01.w};
            unsigned a10[4] = {v10.x,v10.y,v10.z,v10.w}, a11[4] = {v11.x,v11.y,v11.z,v11.w};
            unsigned pk[4];
            #pragma unroll
            for (int e = 0; e < 4; ++e) {
                h2 r = ash2(a00[e])*G00 + ash2(a01[e])*G01
                     + ash2(a10[e])*G10 + ash2(a11[e])*G11;
                pk[e] = ash2u(r);
            }
            lw[(t&1)*128 + (8 + px8)*8 + (oct ^ swz)] = make_uint4(pk[0], pk[1], pk[2], pk[3]);
        }
        // ---- B-read (lgkmcnt auto) + 8 MFMA ----
        #pragma unroll
        for (int ks2 = 0; ks2 < 2; ++ks2) {
            int hg = ks2*4 + q;
            uint4 bu = lw[(t&1)*128 + pc*8 + (hg ^ (pc & 7))];
            half8 bf = *(half8*)&bu;
            #pragma unroll
            for (int cg = 0; cg < 4; ++cg) {
                half8 av = *(const half8*)(g_wh + (size_t)(cg*16 + pc)*576 + (2*t + ks2)*32 + q*8);
                accm[cg] = __builtin_amdgcn_mfma_f32_16x16x32_f16(av, bf, accm[cg], 0, 0, 0);
            }
        }
    }

    // ---- store: D col = pc (= px p0+pc), row = q*4+rr (+cg*16) -> co ----
    #pragma unroll
    for (int cg = 0; cg < 4; ++cg) {
        float4 bv = *(const float4*)(bias + cg*16 + q*4);
        float bb[4] = {bv.x, bv.y, bv.z, bv.w};
        #pragma unroll
        for (int rr = 0; rr < 4; ++rr) {
            int co = cg*16 + q*4 + rr;
            out[((size_t)(b*COd + co)*Hd + i)*Wd + p0 + pc] = accm[cg][rr] + bb[rr];
        }
    }
}

extern "C" void kernel_launch(void* const* d_in, const int* in_sizes, int n_in,
                              void* d_out, int out_size, void* d_ws, size_t ws_size,
                              hipStream_t stream) {
    const float* x      = (const float*)d_in[0];
    const float* w_off  = (const float*)d_in[1];
    const float* b_off  = (const float*)d_in[2];
    const float* weight = (const float*)d_in[3];
    const float* bias   = (const float*)d_in[4];
    float* out = (float*)d_out;

    hipLaunchKernelGGL(k_prep, dim3(692),  dim3(256), 0, stream, x, weight, w_off);
    hipLaunchKernelGGL(k_main, dim3(1024), dim3(256), 0, stream, b_off, bias, out);
}